// Round 7
// baseline (445.467 us; speedup 1.0000x reference)
//
#include <hip/hip_runtime.h>
#include <hip/hip_bf16.h>
#include <hip/hip_cooperative_groups.h>
#include <math.h>

namespace cg = cooperative_groups;

// GAT 2-layer fused pipeline for MI355X (gfx950).
// Round-16: CSR build fused 6 kernels -> 1 cooperative kernel (hist ->
// 3-level scan -> scatter -> ballot finalize) with grid.sync() between
// phases. Edge order and arithmetic identical to r15 -> bit-identical
// output. Targets launch gaps + global round-trips of the 6-dispatch
// chain (hist/scatter ran on 64 blocks with dead time between launches).
// gat_agg (software-pipelined gathers), GEMM (64-row single-pass-A), and
// pack_w byte-identical to r15 for attribution.

#define SLOPE 0.2f

typedef __attribute__((ext_vector_type(8))) __bf16 bf16x8;
typedef __attribute__((ext_vector_type(4))) float f32x4;

__device__ __forceinline__ float gelu_erf(float x) {
    return 0.5f * x * (1.0f + erff(x * 0.70710678118654752f));
}

__device__ __forceinline__ unsigned short f2bf(float f) {  // RNE
    unsigned int u = __float_as_uint(f);
    return (unsigned short)((u + 0x7fffu + ((u >> 16) & 1u)) >> 16);
}
__device__ __forceinline__ float bf2f(unsigned short h) {
    return __uint_as_float((unsigned int)h << 16);
}

// 16-lane (row) all-reduce sum via DPP row_ror 1,2,4,8; every lane of the
// row ends with the row's sum. Chains over different inputs are independent.
__device__ __forceinline__ float row16_sum(float x) {
    x += __int_as_float(__builtin_amdgcn_update_dpp(0, __float_as_int(x), 0x121, 0xF, 0xF, true));
    x += __int_as_float(__builtin_amdgcn_update_dpp(0, __float_as_int(x), 0x122, 0xF, 0xF, true));
    x += __int_as_float(__builtin_amdgcn_update_dpp(0, __float_as_int(x), 0x124, 0xF, 0xF, true));
    x += __int_as_float(__builtin_amdgcn_update_dpp(0, __float_as_int(x), 0x128, 0xF, 0xF, true));
    return x;
}

// XOR swizzle for LDS planes with 256B row stride: spreads the 16-row
// column slice of a ds_read_b128 across 8 distinct 16B slots.
__device__ __forceinline__ int swz(int off) { return off ^ ((off >> 4) & 0x70); }

// ---------------- weight prepack ---------------------------------------------
// Pack index i = ((ct*4+ks)*64 + lane)*8 + j  ->  W[k][n],
// k = ks*32 + (lane>>4)*8 + j,  n = ct*16 + (lane&15).  hi at [i], lo at [CE+i].
__global__ __launch_bounds__(256) void pack_w(
    const float* __restrict__ W0,  const float* __restrict__ Wq1,
    const float* __restrict__ Wp1, const float* __restrict__ Wq2,
    const float* __restrict__ Wp2,
    unsigned short* __restrict__ P0,  unsigned short* __restrict__ Pq1,
    unsigned short* __restrict__ Pp1, unsigned short* __restrict__ Pq2,
    unsigned short* __restrict__ Pp2)
{
    const float* W; unsigned short* P; int C;
    switch (blockIdx.y) {
        case 0:  W = W0;  P = P0;  C = 128; break;
        case 1:  W = Wq1; P = Pq1; C = 128; break;
        case 2:  W = Wp1; P = Pp1; C = 128; break;
        case 3:  W = Wq2; P = Pq2; C = 64;  break;
        default: W = Wp2; P = Pp2; C = 64;  break;
    }
    int i = blockIdx.x * 256 + threadIdx.x;
    int CE = C * 128;
    if (i >= CE) return;
    int j = i & 7, l = (i >> 3) & 63, ks = (i >> 9) & 3, ct = i >> 11;
    int k = ks * 32 + ((l >> 4) << 3) + j;
    int n = ct * 16 + (l & 15);
    float v = W[k * C + n];
    unsigned short hb = f2bf(v);
    P[i] = hb;
    P[CE + i] = f2bf(v - bf2f(hb));
}

// ---------------- MFMA GEMM -------------------------------------------------
// Block = 64 rows x ALL output cols; 4 waves split the col-tiles.
// A panel (64x128, hi+lo bf16 = 32 KB) staged in LDS once (swizzled);
// W fragments streamed from packed global (L2-resident).
// EPI 0: single matrix, out = gelu -> o1hi/o1lo (layer 0, A = fp32).
// EPI 1: TWO matrices: waves 0-1 -> q fp32 (direct), waves 2-3 -> p bf16
//        (LDS-bounced for coalesced 16B stores).
template <int C, bool TWO, int EPI>
__global__ __launch_bounds__(256) void mfma_gemm(
    const float* __restrict__ Af,
    const unsigned short* __restrict__ AHg, const unsigned short* __restrict__ ALg,
    const unsigned short* __restrict__ P1, const float* __restrict__ b1,
    const unsigned short* __restrict__ P2, const float* __restrict__ b2,
    float* __restrict__ outq, unsigned short* __restrict__ outp,
    unsigned short* __restrict__ o1hi, unsigned short* __restrict__ o1lo,
    int N)
{
    constexpr int CE  = C * 128;
    constexpr int CTT = (TWO ? 2 : 1) * (C / 16);   // total col-tiles
    constexpr int CTW = CTT / 4;                    // tiles per wave
    constexpr int QCT = C / 16;                     // tiles in first matrix

    __shared__ __align__(16) unsigned char lds[32768]; // hi plane [0,16K), lo [16K,32K)

    const int t = threadIdx.x;
    const int lane = t & 63;
    const int w = t >> 6;
    const int row0 = blockIdx.x * 64;
    const int mcol = lane & 15;
    const int hk = lane >> 4;

    // ---- stage A (64 rows x 128 dims) as hi/lo bf16 into LDS ----
    if constexpr (EPI == 0) {
#pragma unroll
        for (int i = 0; i < 8; i++) {
            int idx = t + i * 256;            // float4 index, 2048 total
            int row = idx >> 5;               // 32 float4 per row
            int gr = row0 + row;
            float4 v = make_float4(0.f, 0.f, 0.f, 0.f);
            if (gr < N) v = *reinterpret_cast<const float4*>(Af + (size_t)gr * 128 + (idx & 31) * 4);
            const float* f = reinterpret_cast<const float*>(&v);
            unsigned int h[4], l[4];
#pragma unroll
            for (int j = 0; j < 4; j++) {
                unsigned short hb = f2bf(f[j]);
                h[j] = hb;
                l[j] = f2bf(f[j] - bf2f(hb));
            }
            int so = swz(row * 256 + (idx & 31) * 8);
            *reinterpret_cast<uint2*>(&lds[so])         = make_uint2(h[0] | (h[1] << 16), h[2] | (h[3] << 16));
            *reinterpret_cast<uint2*>(&lds[16384 + so]) = make_uint2(l[0] | (l[1] << 16), l[2] | (l[3] << 16));
        }
    } else {
#pragma unroll
        for (int i = 0; i < 4; i++) {
            int idx = t + i * 256;            // uint4 index, 1024 per plane
            int row = idx >> 4;               // 16 uint4 per row
            int gr = row0 + row;
            uint4 vh = make_uint4(0, 0, 0, 0), vl = make_uint4(0, 0, 0, 0);
            if (gr < N) {
                vh = *reinterpret_cast<const uint4*>(AHg + (size_t)gr * 128 + (idx & 15) * 8);
                vl = *reinterpret_cast<const uint4*>(ALg + (size_t)gr * 128 + (idx & 15) * 8);
            }
            int so = swz(row * 256 + (idx & 15) * 16);
            *reinterpret_cast<uint4*>(&lds[so])         = vh;
            *reinterpret_cast<uint4*>(&lds[16384 + so]) = vl;
        }
    }
    __syncthreads();

    f32x4 acc[CTW][4];
#pragma unroll
    for (int c = 0; c < CTW; c++)
#pragma unroll
        for (int rf = 0; rf < 4; rf++) acc[c][rf] = (f32x4){0.f, 0.f, 0.f, 0.f};

#pragma unroll
    for (int ks = 0; ks < 4; ks++) {
        bf16x8 ah[4], al[4];
#pragma unroll
        for (int rf = 0; rf < 4; rf++) {
            int so = swz((rf * 16 + mcol) * 256 + ks * 64 + hk * 16);
            ah[rf] = *reinterpret_cast<const bf16x8*>(&lds[so]);
            al[rf] = *reinterpret_cast<const bf16x8*>(&lds[16384 + so]);
        }
#pragma unroll
        for (int c = 0; c < CTW; c++) {
            int ctg = w * CTW + c;
            bool isq = (!TWO) || (ctg < QCT);
            int ct = isq ? ctg : ctg - QCT;
            const unsigned short* P = isq ? P1 : P2;
            const unsigned short* Wp = P + ((ct * 4 + ks) * 64 + lane) * 8;
            bf16x8 bh = *reinterpret_cast<const bf16x8*>(Wp);
            bf16x8 bl = *reinterpret_cast<const bf16x8*>(Wp + CE);
#pragma unroll
            for (int rf = 0; rf < 4; rf++) {
                acc[c][rf] = __builtin_amdgcn_mfma_f32_16x16x32_bf16(ah[rf], bh, acc[c][rf], 0, 0, 0);
                acc[c][rf] = __builtin_amdgcn_mfma_f32_16x16x32_bf16(al[rf], bh, acc[c][rf], 0, 0, 0);
                acc[c][rf] = __builtin_amdgcn_mfma_f32_16x16x32_bf16(ah[rf], bl, acc[c][rf], 0, 0, 0);
            }
        }
    }

    __syncthreads();   // all A ds_reads done; LDS reused for epilogue staging

    // epilogue: C/D layout col=lane&15, row=(lane>>4)*4+reg
    if constexpr (EPI == 0) {
#pragma unroll
        for (int c = 0; c < CTW; c++) {
            int col = (w * CTW + c) * 16 + mcol;
            float bv = b1[col];
#pragma unroll
            for (int rf = 0; rf < 4; rf++) {
#pragma unroll
                for (int r = 0; r < 4; r++) {
                    int row = rf * 16 + hk * 4 + r;
                    float v = gelu_erf(acc[c][rf][r] + bv);
                    unsigned short hb = f2bf(v);
                    int bo = row * 256 + col * 2;
                    *reinterpret_cast<unsigned short*>(&lds[swz(bo)])         = hb;
                    *reinterpret_cast<unsigned short*>(&lds[16384 + swz(bo)]) = f2bf(v - bf2f(hb));
                }
            }
        }
        __syncthreads();
#pragma unroll
        for (int i = 0; i < 8; i++) {
            int idx = t + i * 256;          // 2048 uint4: hi 0..1023, lo 1024..2047
            int pl = idx >> 10;
            int j = idx & 1023;
            int row = j >> 4;
            int gr = row0 + row;
            if (gr < N) {
                uint4 v = *reinterpret_cast<const uint4*>(&lds[pl * 16384 + swz(row * 256 + (j & 15) * 16)]);
                unsigned short* dp = pl ? o1lo : o1hi;
                *reinterpret_cast<uint4*>(dp + (size_t)gr * 128 + (j & 15) * 8) = v;
            }
        }
    } else {
#pragma unroll
        for (int c = 0; c < CTW; c++) {
            int ctg = w * CTW + c;
            bool isq = ctg < QCT;
            int ct = isq ? ctg : ctg - QCT;
            int col = ct * 16 + mcol;
            float bv = (isq ? b1 : b2)[col];
#pragma unroll
            for (int rf = 0; rf < 4; rf++) {
#pragma unroll
                for (int r = 0; r < 4; r++) {
                    int row = rf * 16 + hk * 4 + r;
                    int gr = row0 + row;
                    float v = acc[c][rf][r] + bv;
                    if (isq) {
                        if (gr < N) outq[(size_t)gr * C + col] = v;   // 4B x 16 lanes = full line
                    } else {
                        *reinterpret_cast<unsigned short*>(&lds[swz(row * 256 + col * 2)]) = f2bf(v);
                    }
                }
            }
        }
        __syncthreads();
        constexpr int SLOTS = C / 8;        // uint4 slots per row (16 or 8)
#pragma unroll
        for (int i = 0; i < (64 * SLOTS) / 256; i++) {
            int idx = t + i * 256;
            int row = idx / SLOTS;
            int sl = idx % SLOTS;
            int gr = row0 + row;
            if (gr < N)
                *reinterpret_cast<uint4*>(outp + (size_t)gr * C + sl * 8) =
                    *reinterpret_cast<const uint4*>(&lds[swz(row * 256 + sl * 16)]);
        }
    }
}

// ---------------- CSR build: ONE cooperative kernel ---------------------------
// 64 blocks x 256 threads, phases separated by grid.sync():
//   A) LDS hist over coarse bins (dst>>4) -> gh[bin*64+blk]  (bin-major)
//   B) exclusive scan over M=CB*64: per-thread register scan (cpt<=16) +
//      block scan of 256 totals + block-0 scan of 64 block totals; final
//      values written once to gscan.
//   C) scatter into bin-grouped pairs via LDS cursors (order == r15).
//   D) ballot finalize: waves loop over bins (zero LDS, zero atomics).
__global__ __launch_bounds__(256) void csr_build(
    const int* __restrict__ src, const int* __restrict__ dst,
    int* __restrict__ gh, int* __restrict__ gscan, int* __restrict__ bsum,
    int2* __restrict__ pairs, int* __restrict__ offs, int* __restrict__ csr_src,
    int N, int E, int CB)
{
    cg::grid_group grid = cg::this_grid();
    __shared__ int smem[4096];
    const int blk = blockIdx.x;     // 0..63
    const int t = threadIdx.x;
    const int lane = t & 63;
    const int M = CB * 64;

    // ---- phase A: coarse histogram ----
    for (int b = t; b < CB; b += 256) smem[b] = 0;
    __syncthreads();
    const int epb = (E + 63) / 64;
    const int es = blk * epb;
    const int ee = (es + epb < E) ? es + epb : E;
    for (int i = es + t; i < ee; i += 256)
        atomicAdd(&smem[dst[i] >> 4], 1);
    __syncthreads();
    for (int b = t; b < CB; b += 256)
        gh[b * 64 + blk] = smem[b];
    __threadfence();
    grid.sync();

    // ---- phase B: exclusive scan gh -> gscan ----
    const int chunk = (M + 63) / 64;           // == CB
    const int c0 = blk * chunk;
    const int c1 = (c0 + chunk < M) ? c0 + chunk : M;
    const int cpt = (chunk + 255) / 256;       // <= 16
    const int bi = c0 + t * cpt;
    int vals[16];
    int tsum = 0;
#pragma unroll
    for (int j = 0; j < 16; j++) {
        if (j < cpt) {
            int i = bi + j;
            int v = (i < c1) ? gh[i] : 0;
            vals[j] = tsum;                     // thread-local exclusive prefix
            tsum += v;
        }
    }
    __syncthreads();                            // smem free (phase A done)
    smem[t] = tsum;
    __syncthreads();
    int x = tsum;
    for (int off = 1; off < 256; off <<= 1) {
        int y = (t >= off) ? smem[t - off] : 0;
        __syncthreads();
        x += y;
        smem[t] = x;
        __syncthreads();
    }
    const int tpref = x - tsum;                 // thread exclusive prefix in block
    if (t == 255) bsum[blk] = x;                // block total
    __threadfence();
    grid.sync();

    if (blk == 0) {                             // scan the 64 block totals
        int v = (t < 64) ? bsum[t] : 0;
        smem[t] = v;
        __syncthreads();
        int x2 = v;
        for (int off = 1; off < 64; off <<= 1) {
            int y = (t >= off && t < 64) ? smem[t - off] : 0;
            __syncthreads();
            x2 += y;
            smem[t] = x2;
            __syncthreads();
        }
        if (t < 64) bsum[t] = x2 - v;           // exclusive
        __threadfence();
    }
    grid.sync();

    const int boff = bsum[blk];
#pragma unroll
    for (int j = 0; j < 16; j++) {
        if (j < cpt) {
            int i = bi + j;
            if (i < c1) gscan[i] = boff + tpref + vals[j];
        }
    }
    __threadfence();
    grid.sync();

    // ---- phase C: scatter into bin-grouped pairs ----
    __syncthreads();
    for (int b = t; b < CB; b += 256)
        smem[b] = gscan[b * 64 + blk];
    __syncthreads();
    for (int i = es + t; i < ee; i += 256) {
        int d = dst[i];
        int sv = src[i];
        int pos = atomicAdd(&smem[d >> 4], 1);  // LDS atomic
        pairs[pos] = make_int2(d, sv);
    }
    __threadfence();
    grid.sync();

    // ---- phase D: ballot finalize (one wave per bin, loop over bins) ----
    const unsigned long long ltmask = (lane == 63) ? ~0ull >> 1
                                                   : (1ull << lane) - 1ull;
    for (int wid = blk * 4 + (t >> 6); wid < CB; wid += 256) {
        const int s    = gscan[wid * 64];
        const int e_   = (wid + 1 < CB) ? gscan[(wid + 1) * 64] : E;
        const int base = wid * 16;

        // pass 1: per-node counts via ballot histogram (rc[j] wave-uniform)
        int rc[16];
#pragma unroll
        for (int j = 0; j < 16; j++) rc[j] = 0;
        for (int cc = s; cc < e_; cc += 64) {
            int i = cc + lane;
            int d = (i < e_) ? pairs[i].x - base : -1;
#pragma unroll
            for (int j = 0; j < 16; j++)
                rc[j] += (int)__popcll(__ballot(d == j));
        }

        int pref[16];
        int run = s;
#pragma unroll
        for (int j = 0; j < 16; j++) { pref[j] = run; run += rc[j]; }
        int pref_v = 0;
#pragma unroll
        for (int j = 0; j < 16; j++) pref_v = (lane == j) ? pref[j] : pref_v;

        if (lane < 16 && base + lane < N) offs[base + lane] = pref_v;
        if (wid == CB - 1 && lane == 16) offs[N] = E;

        // pass 2: stable rank + contiguous scatter
        int rcv = 0;                   // lane j holds running count of node j
        for (int cc = s; cc < e_; cc += 64) {
            int i = cc + lane;
            const bool act = i < e_;
            int2 pr = act ? pairs[i] : make_int2(base - 1, 0);
            int d = pr.x - base;       // -1 for inactive lanes
            unsigned long long msel = 0;
            int addcnt = 0;
#pragma unroll
            for (int j = 0; j < 16; j++) {
                unsigned long long m = __ballot(d == j);
                if (d == j) msel = m;
                if (lane == j) addcnt = (int)__popcll(m);
            }
            int subrank = (int)__popcll(msel & ltmask);
            int posbase = __builtin_amdgcn_ds_bpermute(d * 4, pref_v + rcv);
            if (act) csr_src[posbase + subrank] = pr.y;
            rcv += addcnt;
        }
    }
}

// ---------------- fused GAT edge-softmax + aggregation -----------------------
// 16 lanes per dst node, 4 nodes per wave, 4 edges per group-iteration.
// Software-pipelined: batch i+1's p-row gathers are issued at the top of
// iteration i (kept as raw uint4/uint2 in regs; unpack happens during
// compute), csr indices prefetched 2 batches ahead. The vmcnt wait for
// batch i+1 lands after batch i's ~400cy compute -> gather latency hidden.
// Score partial per edge = fma(d,0.6a)+fma(|d|,0.4a); 4 independent DPP
// row_ror reduce chains; inactive slots masked branchlessly.
// EPI 0 (D=128): m2 = gelu(h+bvec) packed hi/lo bf16.  EPI 1 (D=64): fp32 out.
template <int D, int EPI>
__global__ __launch_bounds__(256) void gat_agg(
    const float* __restrict__ q, const unsigned short* __restrict__ p,
    const float* __restrict__ a, const float* __restrict__ bvec,
    const int* __restrict__ offs, const int* __restrict__ csr_src,
    float* __restrict__ out, unsigned short* __restrict__ mhi,
    unsigned short* __restrict__ mlo, int N)
{
    constexpr int VPL = D / 16;   // dims per lane: 8 (D=128) or 4 (D=64)
    const int t = threadIdx.x;
    const int lane = t & 63;
    const int sl = lane & 15;
    const int base = sl * VPL;
    const int node = blockIdx.x * 16 + ((t >> 6) << 2) + (lane >> 4);
    const bool valid = node < N;

    float qv[VPL], a6[VPL], a4[VPL], acc[VPL];
#pragma unroll
    for (int v = 0; v < VPL; v++) { qv[v] = 0.f; acc[v] = 0.f; }
    if (valid) {
        const float* qp = q + (size_t)node * D + base;
        float4 q0 = *reinterpret_cast<const float4*>(qp);
        qv[0] = q0.x; qv[1] = q0.y; qv[2] = q0.z; qv[3] = q0.w;
        if constexpr (VPL == 8) {
            float4 q1 = *reinterpret_cast<const float4*>(qp + 4);
            qv[4] = q1.x; qv[5] = q1.y; qv[6] = q1.z; qv[7] = q1.w;
        }
    }
#pragma unroll
    for (int v = 0; v < VPL; v++) {
        float av = a[base + v];
        a6[v] = 0.6f * av;
        a4[v] = 0.4f * av;
    }

    // raw-row gather (per-lane 16B / 8B slice of the 16-lane row)
    auto gather = [&](int s) -> uint4 {
        if constexpr (D == 128) {
            return *reinterpret_cast<const uint4*>(p + (size_t)s * 128 + base);
        } else {
            uint2 u = *reinterpret_cast<const uint2*>(p + (size_t)s * 64 + base);
            return make_uint4(u.x, u.y, 0u, 0u);
        }
    };
    auto unpack = [&](uint4 u, float* pv) {
        pv[0] = __uint_as_float(u.x << 16); pv[1] = __uint_as_float(u.x & 0xffff0000u);
        pv[2] = __uint_as_float(u.y << 16); pv[3] = __uint_as_float(u.y & 0xffff0000u);
        if constexpr (VPL == 8) {
            pv[4] = __uint_as_float(u.z << 16); pv[5] = __uint_as_float(u.z & 0xffff0000u);
            pv[6] = __uint_as_float(u.w << 16); pv[7] = __uint_as_float(u.w & 0xffff0000u);
        }
    };

    float denom = 0.f;
    int e  = valid ? offs[node] : 0;
    int e1 = valid ? offs[node + 1] : 0;

    // prologue: batch-0 indices + gathers; batch-1 indices
    int s0 = csr_src[(e + 0 < e1) ? e + 0 : 0];
    int s1 = csr_src[(e + 1 < e1) ? e + 1 : 0];
    int s2 = csr_src[(e + 2 < e1) ? e + 2 : 0];
    int s3 = csr_src[(e + 3 < e1) ? e + 3 : 0];
    uint4 uA0 = gather(s0), uA1 = gather(s1), uA2 = gather(s2), uA3 = gather(s3);
    int en = e + 4;
    int n0 = csr_src[(en + 0 < e1) ? en + 0 : 0];
    int n1 = csr_src[(en + 1 < e1) ? en + 1 : 0];
    int n2 = csr_src[(en + 2 < e1) ? en + 2 : 0];
    int n3 = csr_src[(en + 3 < e1) ? en + 3 : 0];

    while (__any(e < e1)) {
        const bool a0 = (e + 0) < e1, a1b = (e + 1) < e1,
                   a2 = (e + 2) < e1, a3 = (e + 3) < e1;

        // issue NEXT batch's gathers (latency hides under this batch's compute)
        uint4 v0 = gather(n0), v1 = gather(n1), v2 = gather(n2), v3 = gather(n3);

        // prefetch batch+2 csr indices
        const int em = en + 4;
        const int m0 = csr_src[(em + 0 < e1) ? em + 0 : 0];
        const int m1 = csr_src[(em + 1 < e1) ? em + 1 : 0];
        const int m2 = csr_src[(em + 2 < e1) ? em + 2 : 0];
        const int m3 = csr_src[(em + 3 < e1) ? em + 3 : 0];

        // compute on current batch (uA*, already resident)
        float pv[4][VPL];
        unpack(uA0, pv[0]); unpack(uA1, pv[1]); unpack(uA2, pv[2]); unpack(uA3, pv[3]);

        float pa0 = 0.f, pa1 = 0.f, pa2 = 0.f, pa3 = 0.f;
#pragma unroll
        for (int v = 0; v < VPL; v++) {
            float d0 = qv[v] + pv[0][v];
            float d1 = qv[v] + pv[1][v];
            float d2 = qv[v] + pv[2][v];
            float d3 = qv[v] + pv[3][v];
            pa0 = fmaf(d0, a6[v], pa0); pa0 = fmaf(fabsf(d0), a4[v], pa0);
            pa1 = fmaf(d1, a6[v], pa1); pa1 = fmaf(fabsf(d1), a4[v], pa1);
            pa2 = fmaf(d2, a6[v], pa2); pa2 = fmaf(fabsf(d2), a4[v], pa2);
            pa3 = fmaf(d3, a6[v], pa3); pa3 = fmaf(fabsf(d3), a4[v], pa3);
        }

        float r0 = row16_sum(pa0);
        float r1 = row16_sum(pa1);
        float r2 = row16_sum(pa2);
        float r3 = row16_sum(pa3);

        float esm0 = a0  ? __expf(r0) : 0.f;
        float esm1 = a1b ? __expf(r1) : 0.f;
        float esm2 = a2  ? __expf(r2) : 0.f;
        float esm3 = a3  ? __expf(r3) : 0.f;
        denom += (esm0 + esm1) + (esm2 + esm3);
#pragma unroll
        for (int v = 0; v < VPL; v++) {
            acc[v] = fmaf(esm0, pv[0][v], acc[v]);
            acc[v] = fmaf(esm1, pv[1][v], acc[v]);
            acc[v] = fmaf(esm2, pv[2][v], acc[v]);
            acc[v] = fmaf(esm3, pv[3][v], acc[v]);
        }

        // rotate pipeline
        uA0 = v0; uA1 = v1; uA2 = v2; uA3 = v3;
        n0 = m0; n1 = m1; n2 = m2; n3 = m3;
        e = en; en = em;
    }

    if (!valid) return;
    float inv = (denom != 0.f) ? 1.f / denom : 0.f;  // zero-degree -> agg = 0
    if constexpr (EPI == 0) {
        union { unsigned short us[8]; uint4 v; } H, L;
#pragma unroll
        for (int v = 0; v < VPL; v++) {
            float g = gelu_erf(acc[v] * inv + bvec[base + v]);
            H.us[v] = f2bf(g);
            L.us[v] = f2bf(g - bf2f(H.us[v]));
        }
        *reinterpret_cast<uint4*>(mhi + (size_t)node * 128 + base) = H.v;
        *reinterpret_cast<uint4*>(mlo + (size_t)node * 128 + base) = L.v;
    } else {
        union { float f[4]; float4 v; } O;
#pragma unroll
        for (int v = 0; v < VPL; v++) O.f[v] = acc[v] * inv + bvec[base + v];
        *reinterpret_cast<float4*>(out + (size_t)node * D + base) = O.v;
    }
}

// ---------------- launch ------------------------------------------------------
extern "C" void kernel_launch(void* const* d_in, const int* in_sizes, int n_in,
                              void* d_out, int out_size, void* d_ws, size_t ws_size,
                              hipStream_t stream)
{
    const float* x     = (const float*)d_in[0];
    const float* W0    = (const float*)d_in[1];
    const float* b0    = (const float*)d_in[2];
    const float* Wq1   = (const float*)d_in[3];
    const float* bq1   = (const float*)d_in[4];
    const float* Wp1   = (const float*)d_in[5];
    const float* bp1   = (const float*)d_in[6];
    const float* a1    = (const float*)d_in[7];
    const float* bg2   = (const float*)d_in[8];
    const float* Wq2   = (const float*)d_in[9];
    const float* bq2   = (const float*)d_in[10];
    const float* Wp2   = (const float*)d_in[11];
    const float* bp2   = (const float*)d_in[12];
    const float* a2    = (const float*)d_in[13];
    const float* b_out = (const float*)d_in[14];
    const int*   src   = (const int*)d_in[15];
    const int*   dst   = (const int*)d_in[16];

    const int N = in_sizes[0] / 128;
    const int E = in_sizes[15];
    float* out = (float*)d_out;

    // workspace carve
    float* q_buf        = (float*)d_ws;                      // N*128 f32
    unsigned short* pb  = (unsigned short*)(q_buf + (size_t)N * 128);  // N*128 bf16
    unsigned short* Mhi = pb + (size_t)N * 128;
    unsigned short* Mlo = Mhi + (size_t)N * 128;
    unsigned short* P0  = Mlo + (size_t)N * 128;
    unsigned short* Pq1 = P0  + 128 * 128 * 2;
    unsigned short* Pp1 = Pq1 + 128 * 128 * 2;
    unsigned short* Pq2 = Pp1 + 128 * 128 * 2;
    unsigned short* Pp2 = Pq2 + 128 * 64 * 2;
    int* offs    = (int*)(Pp2 + 128 * 64 * 2);
    int* csr_src = offs + (N + 2);
    const int CB = (N + 15) / 16;          // coarse bins (<= 4096 for N<=65536)
    const int M  = CB * 64;
    int* gh    = csr_src + E;
    int* gscan = gh + M;
    int* bsum  = gscan + M;                // 64 ints used
    // pairs aliases q_buf (dead until gemm layer-1); int2-aligned (base of ws)
    int2* pairs = (int2*)q_buf;

    // 1) weight prepack
    pack_w<<<dim3(64, 5), 256, 0, stream>>>(W0, Wq1, Wp1, Wq2, Wp2,
                                            P0, Pq1, Pp1, Pq2, Pp2);
    // 2) CSR build: single cooperative kernel (hist -> scan -> scatter -> finalize)
    {
        void* args[] = {
            (void*)&src, (void*)&dst, (void*)&gh, (void*)&gscan, (void*)&bsum,
            (void*)&pairs, (void*)&offs, (void*)&csr_src,
            (void*)&N, (void*)&E, (void*)&CB
        };
        hipLaunchCooperativeKernel((const void*)csr_build, dim3(64), dim3(256),
                                   args, 0, stream);
    }

    const int GB64 = (N + 63) / 64;
    const int GGAT = (N + 15) / 16;

    // 3) layer 0: m1 = gelu(x@W0 + b0) -> Mhi/Mlo
    mfma_gemm<128, false, 0><<<GB64, 256, 0, stream>>>(
        x, nullptr, nullptr, P0, b0, nullptr, nullptr,
        nullptr, nullptr, Mhi, Mlo, N);
    // 4) layer 1 projections: q1 fp32 + p1 bf16 in ONE pass over A
    mfma_gemm<128, true, 1><<<GB64, 256, 0, stream>>>(
        nullptr, Mhi, Mlo, Pq1, bq1, Pp1, bp1,
        q_buf, pb, nullptr, nullptr, N);
    // 5) layer 1 GAT -> m2 = gelu(h1 + bg2) -> Mhi/Mlo
    gat_agg<128, 0><<<GGAT, 256, 0, stream>>>(
        q_buf, pb, a1, bg2, offs, csr_src,
        nullptr, Mhi, Mlo, N);
    // 6) layer 2 projections: q2 fp32 + p2 bf16 in ONE pass over A
    mfma_gemm<64, true, 1><<<GB64, 256, 0, stream>>>(
        nullptr, Mhi, Mlo, Pq2, bq2, Pp2, bp2,
        q_buf, pb, nullptr, nullptr, N);
    // 7) layer 2 GAT + b_out -> d_out
    gat_agg<64, 1><<<GGAT, 256, 0, stream>>>(
        q_buf, pb, a2, b_out, offs, csr_src,
        out, nullptr, nullptr, N);
}

// Round 8
// 289.951 us; speedup vs baseline: 1.5364x; 1.5364x over previous
//
#include <hip/hip_runtime.h>
#include <hip/hip_bf16.h>
#include <math.h>

// GAT 2-layer fused pipeline for MI355X (gfx950).
// Round-17: full revert of r16's cooperative CSR fusion (64-block shape
// starved finalize: occupancy 2.8%, 185us). Back to r15's 6-kernel CSR
// chain (all sub-46us). gat_agg deepened to 8-edges-in-flight (2 batches
// of 4): compute batch i, batch i+1 resident in regs, batch i+2 gathers
// issuing -> issue->use ~800cy matches random-gather latency (r15's
// 4-deep only reached 64% VALUBusy; one-iteration distance ~400cy was
// shorter than the ~600-900cy L3/HBM latency). VGPR ~100 caps occupancy
// at 16 waves/CU >= measured ~12 -> no loss. Arithmetic order unchanged.
// GEMM (64-row single-pass-A), CSR build, ballot finalize == r15.

#define SLOPE 0.2f

typedef __attribute__((ext_vector_type(8))) __bf16 bf16x8;
typedef __attribute__((ext_vector_type(4))) float f32x4;

__device__ __forceinline__ float gelu_erf(float x) {
    return 0.5f * x * (1.0f + erff(x * 0.70710678118654752f));
}

__device__ __forceinline__ unsigned short f2bf(float f) {  // RNE
    unsigned int u = __float_as_uint(f);
    return (unsigned short)((u + 0x7fffu + ((u >> 16) & 1u)) >> 16);
}
__device__ __forceinline__ float bf2f(unsigned short h) {
    return __uint_as_float((unsigned int)h << 16);
}

// 16-lane (row) all-reduce sum via DPP row_ror 1,2,4,8; every lane of the
// row ends with the row's sum. Chains over different inputs are independent.
__device__ __forceinline__ float row16_sum(float x) {
    x += __int_as_float(__builtin_amdgcn_update_dpp(0, __float_as_int(x), 0x121, 0xF, 0xF, true));
    x += __int_as_float(__builtin_amdgcn_update_dpp(0, __float_as_int(x), 0x122, 0xF, 0xF, true));
    x += __int_as_float(__builtin_amdgcn_update_dpp(0, __float_as_int(x), 0x124, 0xF, 0xF, true));
    x += __int_as_float(__builtin_amdgcn_update_dpp(0, __float_as_int(x), 0x128, 0xF, 0xF, true));
    return x;
}

// XOR swizzle for LDS planes with 256B row stride: spreads the 16-row
// column slice of a ds_read_b128 across 8 distinct 16B slots.
__device__ __forceinline__ int swz(int off) { return off ^ ((off >> 4) & 0x70); }

// ---------------- weight prepack ---------------------------------------------
// Pack index i = ((ct*4+ks)*64 + lane)*8 + j  ->  W[k][n],
// k = ks*32 + (lane>>4)*8 + j,  n = ct*16 + (lane&15).  hi at [i], lo at [CE+i].
__global__ __launch_bounds__(256) void pack_w(
    const float* __restrict__ W0,  const float* __restrict__ Wq1,
    const float* __restrict__ Wp1, const float* __restrict__ Wq2,
    const float* __restrict__ Wp2,
    unsigned short* __restrict__ P0,  unsigned short* __restrict__ Pq1,
    unsigned short* __restrict__ Pp1, unsigned short* __restrict__ Pq2,
    unsigned short* __restrict__ Pp2)
{
    const float* W; unsigned short* P; int C;
    switch (blockIdx.y) {
        case 0:  W = W0;  P = P0;  C = 128; break;
        case 1:  W = Wq1; P = Pq1; C = 128; break;
        case 2:  W = Wp1; P = Pp1; C = 128; break;
        case 3:  W = Wq2; P = Pq2; C = 64;  break;
        default: W = Wp2; P = Pp2; C = 64;  break;
    }
    int i = blockIdx.x * 256 + threadIdx.x;
    int CE = C * 128;
    if (i >= CE) return;
    int j = i & 7, l = (i >> 3) & 63, ks = (i >> 9) & 3, ct = i >> 11;
    int k = ks * 32 + ((l >> 4) << 3) + j;
    int n = ct * 16 + (l & 15);
    float v = W[k * C + n];
    unsigned short hb = f2bf(v);
    P[i] = hb;
    P[CE + i] = f2bf(v - bf2f(hb));
}

// ---------------- MFMA GEMM -------------------------------------------------
// Block = 64 rows x ALL output cols; 4 waves split the col-tiles.
// A panel (64x128, hi+lo bf16 = 32 KB) staged in LDS once (swizzled);
// W fragments streamed from packed global (L2-resident).
// EPI 0: single matrix, out = gelu -> o1hi/o1lo (layer 0, A = fp32).
// EPI 1: TWO matrices: waves 0-1 -> q fp32 (direct), waves 2-3 -> p bf16
//        (LDS-bounced for coalesced 16B stores).
template <int C, bool TWO, int EPI>
__global__ __launch_bounds__(256) void mfma_gemm(
    const float* __restrict__ Af,
    const unsigned short* __restrict__ AHg, const unsigned short* __restrict__ ALg,
    const unsigned short* __restrict__ P1, const float* __restrict__ b1,
    const unsigned short* __restrict__ P2, const float* __restrict__ b2,
    float* __restrict__ outq, unsigned short* __restrict__ outp,
    unsigned short* __restrict__ o1hi, unsigned short* __restrict__ o1lo,
    int N)
{
    constexpr int CE  = C * 128;
    constexpr int CTT = (TWO ? 2 : 1) * (C / 16);   // total col-tiles
    constexpr int CTW = CTT / 4;                    // tiles per wave
    constexpr int QCT = C / 16;                     // tiles in first matrix

    __shared__ __align__(16) unsigned char lds[32768]; // hi plane [0,16K), lo [16K,32K)

    const int t = threadIdx.x;
    const int lane = t & 63;
    const int w = t >> 6;
    const int row0 = blockIdx.x * 64;
    const int mcol = lane & 15;
    const int hk = lane >> 4;

    // ---- stage A (64 rows x 128 dims) as hi/lo bf16 into LDS ----
    if constexpr (EPI == 0) {
#pragma unroll
        for (int i = 0; i < 8; i++) {
            int idx = t + i * 256;            // float4 index, 2048 total
            int row = idx >> 5;               // 32 float4 per row
            int gr = row0 + row;
            float4 v = make_float4(0.f, 0.f, 0.f, 0.f);
            if (gr < N) v = *reinterpret_cast<const float4*>(Af + (size_t)gr * 128 + (idx & 31) * 4);
            const float* f = reinterpret_cast<const float*>(&v);
            unsigned int h[4], l[4];
#pragma unroll
            for (int j = 0; j < 4; j++) {
                unsigned short hb = f2bf(f[j]);
                h[j] = hb;
                l[j] = f2bf(f[j] - bf2f(hb));
            }
            int so = swz(row * 256 + (idx & 31) * 8);
            *reinterpret_cast<uint2*>(&lds[so])         = make_uint2(h[0] | (h[1] << 16), h[2] | (h[3] << 16));
            *reinterpret_cast<uint2*>(&lds[16384 + so]) = make_uint2(l[0] | (l[1] << 16), l[2] | (l[3] << 16));
        }
    } else {
#pragma unroll
        for (int i = 0; i < 4; i++) {
            int idx = t + i * 256;            // uint4 index, 1024 per plane
            int row = idx >> 4;               // 16 uint4 per row
            int gr = row0 + row;
            uint4 vh = make_uint4(0, 0, 0, 0), vl = make_uint4(0, 0, 0, 0);
            if (gr < N) {
                vh = *reinterpret_cast<const uint4*>(AHg + (size_t)gr * 128 + (idx & 15) * 8);
                vl = *reinterpret_cast<const uint4*>(ALg + (size_t)gr * 128 + (idx & 15) * 8);
            }
            int so = swz(row * 256 + (idx & 15) * 16);
            *reinterpret_cast<uint4*>(&lds[so])         = vh;
            *reinterpret_cast<uint4*>(&lds[16384 + so]) = vl;
        }
    }
    __syncthreads();

    f32x4 acc[CTW][4];
#pragma unroll
    for (int c = 0; c < CTW; c++)
#pragma unroll
        for (int rf = 0; rf < 4; rf++) acc[c][rf] = (f32x4){0.f, 0.f, 0.f, 0.f};

#pragma unroll
    for (int ks = 0; ks < 4; ks++) {
        bf16x8 ah[4], al[4];
#pragma unroll
        for (int rf = 0; rf < 4; rf++) {
            int so = swz((rf * 16 + mcol) * 256 + ks * 64 + hk * 16);
            ah[rf] = *reinterpret_cast<const bf16x8*>(&lds[so]);
            al[rf] = *reinterpret_cast<const bf16x8*>(&lds[16384 + so]);
        }
#pragma unroll
        for (int c = 0; c < CTW; c++) {
            int ctg = w * CTW + c;
            bool isq = (!TWO) || (ctg < QCT);
            int ct = isq ? ctg : ctg - QCT;
            const unsigned short* P = isq ? P1 : P2;
            const unsigned short* Wp = P + ((ct * 4 + ks) * 64 + lane) * 8;
            bf16x8 bh = *reinterpret_cast<const bf16x8*>(Wp);
            bf16x8 bl = *reinterpret_cast<const bf16x8*>(Wp + CE);
#pragma unroll
            for (int rf = 0; rf < 4; rf++) {
                acc[c][rf] = __builtin_amdgcn_mfma_f32_16x16x32_bf16(ah[rf], bh, acc[c][rf], 0, 0, 0);
                acc[c][rf] = __builtin_amdgcn_mfma_f32_16x16x32_bf16(al[rf], bh, acc[c][rf], 0, 0, 0);
                acc[c][rf] = __builtin_amdgcn_mfma_f32_16x16x32_bf16(ah[rf], bl, acc[c][rf], 0, 0, 0);
            }
        }
    }

    __syncthreads();   // all A ds_reads done; LDS reused for epilogue staging

    // epilogue: C/D layout col=lane&15, row=(lane>>4)*4+reg
    if constexpr (EPI == 0) {
#pragma unroll
        for (int c = 0; c < CTW; c++) {
            int col = (w * CTW + c) * 16 + mcol;
            float bv = b1[col];
#pragma unroll
            for (int rf = 0; rf < 4; rf++) {
#pragma unroll
                for (int r = 0; r < 4; r++) {
                    int row = rf * 16 + hk * 4 + r;
                    float v = gelu_erf(acc[c][rf][r] + bv);
                    unsigned short hb = f2bf(v);
                    int bo = row * 256 + col * 2;
                    *reinterpret_cast<unsigned short*>(&lds[swz(bo)])         = hb;
                    *reinterpret_cast<unsigned short*>(&lds[16384 + swz(bo)]) = f2bf(v - bf2f(hb));
                }
            }
        }
        __syncthreads();
#pragma unroll
        for (int i = 0; i < 8; i++) {
            int idx = t + i * 256;          // 2048 uint4: hi 0..1023, lo 1024..2047
            int pl = idx >> 10;
            int j = idx & 1023;
            int row = j >> 4;
            int gr = row0 + row;
            if (gr < N) {
                uint4 v = *reinterpret_cast<const uint4*>(&lds[pl * 16384 + swz(row * 256 + (j & 15) * 16)]);
                unsigned short* dp = pl ? o1lo : o1hi;
                *reinterpret_cast<uint4*>(dp + (size_t)gr * 128 + (j & 15) * 8) = v;
            }
        }
    } else {
#pragma unroll
        for (int c = 0; c < CTW; c++) {
            int ctg = w * CTW + c;
            bool isq = ctg < QCT;
            int ct = isq ? ctg : ctg - QCT;
            int col = ct * 16 + mcol;
            float bv = (isq ? b1 : b2)[col];
#pragma unroll
            for (int rf = 0; rf < 4; rf++) {
#pragma unroll
                for (int r = 0; r < 4; r++) {
                    int row = rf * 16 + hk * 4 + r;
                    int gr = row0 + row;
                    float v = acc[c][rf][r] + bv;
                    if (isq) {
                        if (gr < N) outq[(size_t)gr * C + col] = v;   // 4B x 16 lanes = full line
                    } else {
                        *reinterpret_cast<unsigned short*>(&lds[swz(row * 256 + col * 2)]) = f2bf(v);
                    }
                }
            }
        }
        __syncthreads();
        constexpr int SLOTS = C / 8;        // uint4 slots per row (16 or 8)
#pragma unroll
        for (int i = 0; i < (64 * SLOTS) / 256; i++) {
            int idx = t + i * 256;
            int row = idx / SLOTS;
            int sl = idx % SLOTS;
            int gr = row0 + row;
            if (gr < N)
                *reinterpret_cast<uint4*>(outp + (size_t)gr * C + sl * 8) =
                    *reinterpret_cast<const uint4*>(&lds[swz(row * 256 + sl * 16)]);
        }
    }
}

// ---------------- CSR build: atomic-free two-level counting sort -------------
// Coarse bin = dst >> 4 (16 nodes per bin), CB = ceil(N/16) <= 4096.
// 64 edge-blocks; gh[bin*64 + blk] = count (bin-major for linear scan).

__global__ __launch_bounds__(256) void hist_coarse(
    const int* __restrict__ dst, int* __restrict__ gh, int E, int CB)
{
    __shared__ int cnt[4096];
    const int blk = blockIdx.x;     // 0..63
    const int t = threadIdx.x;
    for (int b = t; b < CB; b += 256) cnt[b] = 0;
    __syncthreads();
    const int epb = (E + 63) / 64;
    const int s = blk * epb;
    const int e_ = (s + epb < E) ? s + epb : E;
    for (int i = s + t; i < e_; i += 256)
        atomicAdd(&cnt[dst[i] >> 4], 1);
    __syncthreads();
    for (int b = t; b < CB; b += 256)
        gh[b * 64 + blk] = cnt[b];
}

// hierarchical exclusive scan over M = CB*64 values: gh -> gscan
__global__ __launch_bounds__(256) void scan1_kernel(const int* __restrict__ gh,
                                                    int* __restrict__ gscan,
                                                    int* __restrict__ bsum, int M)
{
    __shared__ int lds[256];
    int t = threadIdx.x;
    int i = blockIdx.x * 256 + t;
    int v = (i < M) ? gh[i] : 0;
    lds[t] = v;
    __syncthreads();
    int x = v;
    for (int off = 1; off < 256; off <<= 1) {
        int y = (t >= off) ? lds[t - off] : 0;
        __syncthreads();
        x += y;
        lds[t] = x;
        __syncthreads();
    }
    if (i < M) gscan[i] = x - v;
    if (t == 255) bsum[blockIdx.x] = x;
}

__global__ __launch_bounds__(1024) void scan2_kernel(int* __restrict__ bsum, int NB)
{
    __shared__ int lds[1024];
    int t = threadIdx.x;
    int v = (t < NB) ? bsum[t] : 0;
    lds[t] = v;
    __syncthreads();
    int x = v;
    for (int off = 1; off < 1024; off <<= 1) {
        int y = (t >= off) ? lds[t - off] : 0;
        __syncthreads();
        x += y;
        lds[t] = x;
        __syncthreads();
    }
    if (t < NB) bsum[t] = x - v;
}

__global__ __launch_bounds__(256) void scan3_kernel(int* __restrict__ gscan,
                                                    const int* __restrict__ bsum, int M)
{
    int i = blockIdx.x * 256 + threadIdx.x;
    if (i < M) gscan[i] += bsum[blockIdx.x];
}

// scatter edges into coarse-bin-grouped (dst,src) pairs; LDS cursors only.
__global__ __launch_bounds__(256) void scatter_coarse(
    const int* __restrict__ src, const int* __restrict__ dst,
    const int* __restrict__ gscan, int2* __restrict__ pairs, int E, int CB)
{
    __shared__ int cur[4096];
    const int blk = blockIdx.x;     // 0..63
    const int t = threadIdx.x;
    for (int b = t; b < CB; b += 256)
        cur[b] = gscan[b * 64 + blk];
    __syncthreads();
    const int epb = (E + 63) / 64;
    const int s = blk * epb;
    const int e_ = (s + epb < E) ? s + epb : E;
    for (int i = s + t; i < e_; i += 256) {
        int d = dst[i];
        int sv = src[i];
        int pos = atomicAdd(&cur[d >> 4], 1);   // LDS atomic
        pairs[pos] = make_int2(d, sv);
    }
}

// one WAVE per coarse bin: ballot-histogram counts, exclusive scan, stable
// ranks via popcount(ballot & lanemask_lt) + per-chunk running cursor in
// lane j (fetched per-lane with one ds_bpermute). Zero LDS, zero atomics.
__global__ __launch_bounds__(256) void finalize_kernel(
    const int2* __restrict__ pairs, const int* __restrict__ gscan,
    int* __restrict__ offs, int* __restrict__ csr_src, int N, int E, int CB)
{
    const int wid = blockIdx.x * 4 + (threadIdx.x >> 6);   // bin index
    const int lane = threadIdx.x & 63;
    if (wid >= CB) return;                                 // wave-uniform exit

    const int s    = gscan[wid * 64];
    const int e_   = (wid + 1 < CB) ? gscan[(wid + 1) * 64] : E;
    const int base = wid * 16;
    const unsigned long long ltmask = (lane == 63) ? ~0ull >> 1
                                                   : (1ull << lane) - 1ull;

    // pass 1: per-node counts via ballot histogram (rc[j] wave-uniform)
    int rc[16];
#pragma unroll
    for (int j = 0; j < 16; j++) rc[j] = 0;
    for (int c0 = s; c0 < e_; c0 += 64) {
        int i = c0 + lane;
        int d = (i < e_) ? pairs[i].x - base : -1;
#pragma unroll
        for (int j = 0; j < 16; j++)
            rc[j] += (int)__popcll(__ballot(d == j));
    }

    // exclusive scan -> pref[]; vector copy in lane j for bpermute lookups
    int pref[16];
    int run = s;
#pragma unroll
    for (int j = 0; j < 16; j++) { pref[j] = run; run += rc[j]; }
    int pref_v = 0;
#pragma unroll
    for (int j = 0; j < 16; j++) pref_v = (lane == j) ? pref[j] : pref_v;

    if (lane < 16 && base + lane < N) offs[base + lane] = pref_v;
    if (wid == CB - 1 && lane == 16) offs[N] = E;

    // pass 2: stable rank + contiguous scatter
    int rcv = 0;                       // lane j holds running count of node j
    for (int c0 = s; c0 < e_; c0 += 64) {
        int i = c0 + lane;
        const bool act = i < e_;
        int2 pr = act ? pairs[i] : make_int2(base - 1, 0);
        int d = pr.x - base;           // -1 for inactive lanes
        unsigned long long msel = 0;
        int addcnt = 0;
#pragma unroll
        for (int j = 0; j < 16; j++) {
            unsigned long long m = __ballot(d == j);
            if (d == j) msel = m;
            if (lane == j) addcnt = (int)__popcll(m);
        }
        int subrank = (int)__popcll(msel & ltmask);
        int posbase = __builtin_amdgcn_ds_bpermute(d * 4, pref_v + rcv);
        if (act) csr_src[posbase + subrank] = pr.y;
        rcv += addcnt;
    }
}

// ---------------- fused GAT edge-softmax + aggregation -----------------------
// 16 lanes per dst node, 4 nodes per wave, 4 edges computed per iteration,
// 8 edges in flight (2-batch software pipeline): compute batch i from regs
// while batch i+1 is resident and batch i+2's gathers are issuing; csr
// indices prefetched 3 batches ahead. Issue->use distance ~2 compute
// phases (~800cy) covers the random-gather L3/HBM latency. Idle slots
// clamp to csr_src[0] (hot row, near-free). Score partial per edge =
// fma(d,0.6a)+fma(|d|,0.4a); 4 independent DPP row_ror reduce chains;
// inactive slots masked branchlessly.
// EPI 0 (D=128): m2 = gelu(h+bvec) packed hi/lo bf16.  EPI 1 (D=64): fp32 out.
template <int D, int EPI>
__global__ __launch_bounds__(256) void gat_agg(
    const float* __restrict__ q, const unsigned short* __restrict__ p,
    const float* __restrict__ a, const float* __restrict__ bvec,
    const int* __restrict__ offs, const int* __restrict__ csr_src,
    float* __restrict__ out, unsigned short* __restrict__ mhi,
    unsigned short* __restrict__ mlo, int N)
{
    constexpr int VPL = D / 16;   // dims per lane: 8 (D=128) or 4 (D=64)
    const int t = threadIdx.x;
    const int lane = t & 63;
    const int sl = lane & 15;
    const int base = sl * VPL;
    const int node = blockIdx.x * 16 + ((t >> 6) << 2) + (lane >> 4);
    const bool valid = node < N;

    float qv[VPL], a6[VPL], a4[VPL], acc[VPL];
#pragma unroll
    for (int v = 0; v < VPL; v++) { qv[v] = 0.f; acc[v] = 0.f; }
    if (valid) {
        const float* qp = q + (size_t)node * D + base;
        float4 q0 = *reinterpret_cast<const float4*>(qp);
        qv[0] = q0.x; qv[1] = q0.y; qv[2] = q0.z; qv[3] = q0.w;
        if constexpr (VPL == 8) {
            float4 q1 = *reinterpret_cast<const float4*>(qp + 4);
            qv[4] = q1.x; qv[5] = q1.y; qv[6] = q1.z; qv[7] = q1.w;
        }
    }
#pragma unroll
    for (int v = 0; v < VPL; v++) {
        float av = a[base + v];
        a6[v] = 0.6f * av;
        a4[v] = 0.4f * av;
    }

    // raw-row gather (per-lane 16B / 8B slice of the 16-lane row)
    auto gather = [&](int s) -> uint4 {
        if constexpr (D == 128) {
            return *reinterpret_cast<const uint4*>(p + (size_t)s * 128 + base);
        } else {
            uint2 u = *reinterpret_cast<const uint2*>(p + (size_t)s * 64 + base);
            return make_uint4(u.x, u.y, 0u, 0u);
        }
    };
    auto unpack = [&](uint4 u, float* pv) {
        pv[0] = __uint_as_float(u.x << 16); pv[1] = __uint_as_float(u.x & 0xffff0000u);
        pv[2] = __uint_as_float(u.y << 16); pv[3] = __uint_as_float(u.y & 0xffff0000u);
        if constexpr (VPL == 8) {
            pv[4] = __uint_as_float(u.z << 16); pv[5] = __uint_as_float(u.z & 0xffff0000u);
            pv[6] = __uint_as_float(u.w << 16); pv[7] = __uint_as_float(u.w & 0xffff0000u);
        }
    };

    float denom = 0.f;
    int e  = valid ? offs[node] : 0;
    int e1 = valid ? offs[node + 1] : 0;

    // prologue: batches 0 and 1 gathered, batch 2 indices prefetched
    int s0 = csr_src[(e + 0 < e1) ? e + 0 : 0];
    int s1 = csr_src[(e + 1 < e1) ? e + 1 : 0];
    int s2 = csr_src[(e + 2 < e1) ? e + 2 : 0];
    int s3 = csr_src[(e + 3 < e1) ? e + 3 : 0];
    uint4 uA0 = gather(s0), uA1 = gather(s1), uA2 = gather(s2), uA3 = gather(s3);
    int eb = e + 4;
    int b0 = csr_src[(eb + 0 < e1) ? eb + 0 : 0];
    int b1 = csr_src[(eb + 1 < e1) ? eb + 1 : 0];
    int b2 = csr_src[(eb + 2 < e1) ? eb + 2 : 0];
    int b3 = csr_src[(eb + 3 < e1) ? eb + 3 : 0];
    uint4 uB0 = gather(b0), uB1 = gather(b1), uB2 = gather(b2), uB3 = gather(b3);
    int ec = e + 8;
    int c0 = csr_src[(ec + 0 < e1) ? ec + 0 : 0];
    int c1 = csr_src[(ec + 1 < e1) ? ec + 1 : 0];
    int c2 = csr_src[(ec + 2 < e1) ? ec + 2 : 0];
    int c3 = csr_src[(ec + 3 < e1) ? ec + 3 : 0];

    while (__any(e < e1)) {
        const bool a0 = (e + 0) < e1, a1c = (e + 1) < e1,
                   a2 = (e + 2) < e1, a3 = (e + 3) < e1;

        // issue batch i+2's gathers (use is 2 compute phases away)
        uint4 vC0 = gather(c0), vC1 = gather(c1), vC2 = gather(c2), vC3 = gather(c3);

        // prefetch batch i+3's csr indices
        const int ed = ec + 4;
        const int d0 = csr_src[(ed + 0 < e1) ? ed + 0 : 0];
        const int d1 = csr_src[(ed + 1 < e1) ? ed + 1 : 0];
        const int d2 = csr_src[(ed + 2 < e1) ? ed + 2 : 0];
        const int d3 = csr_src[(ed + 3 < e1) ? ed + 3 : 0];

        // compute on batch i (uA*, loaded 2 iterations ago)
        float pv[4][VPL];
        unpack(uA0, pv[0]); unpack(uA1, pv[1]); unpack(uA2, pv[2]); unpack(uA3, pv[3]);

        float pa0 = 0.f, pa1 = 0.f, pa2 = 0.f, pa3 = 0.f;
#pragma unroll
        for (int v = 0; v < VPL; v++) {
            float dd0 = qv[v] + pv[0][v];
            float dd1 = qv[v] + pv[1][v];
            float dd2 = qv[v] + pv[2][v];
            float dd3 = qv[v] + pv[3][v];
            pa0 = fmaf(dd0, a6[v], pa0); pa0 = fmaf(fabsf(dd0), a4[v], pa0);
            pa1 = fmaf(dd1, a6[v], pa1); pa1 = fmaf(fabsf(dd1), a4[v], pa1);
            pa2 = fmaf(dd2, a6[v], pa2); pa2 = fmaf(fabsf(dd2), a4[v], pa2);
            pa3 = fmaf(dd3, a6[v], pa3); pa3 = fmaf(fabsf(dd3), a4[v], pa3);
        }

        float r0 = row16_sum(pa0);
        float r1 = row16_sum(pa1);
        float r2 = row16_sum(pa2);
        float r3 = row16_sum(pa3);

        float esm0 = a0  ? __expf(r0) : 0.f;
        float esm1 = a1c ? __expf(r1) : 0.f;
        float esm2 = a2  ? __expf(r2) : 0.f;
        float esm3 = a3  ? __expf(r3) : 0.f;
        denom += (esm0 + esm1) + (esm2 + esm3);
#pragma unroll
        for (int v = 0; v < VPL; v++) {
            acc[v] = fmaf(esm0, pv[0][v], acc[v]);
            acc[v] = fmaf(esm1, pv[1][v], acc[v]);
            acc[v] = fmaf(esm2, pv[2][v], acc[v]);
            acc[v] = fmaf(esm3, pv[3][v], acc[v]);
        }

        // rotate 2-deep pipeline
        uA0 = uB0; uA1 = uB1; uA2 = uB2; uA3 = uB3;
        uB0 = vC0; uB1 = vC1; uB2 = vC2; uB3 = vC3;
        c0 = d0; c1 = d1; c2 = d2; c3 = d3;
        e = eb; eb = ec; ec = ed;
    }

    if (!valid) return;
    float inv = (denom != 0.f) ? 1.f / denom : 0.f;  // zero-degree -> agg = 0
    if constexpr (EPI == 0) {
        union { unsigned short us[8]; uint4 v; } H, L;
#pragma unroll
        for (int v = 0; v < VPL; v++) {
            float g = gelu_erf(acc[v] * inv + bvec[base + v]);
            H.us[v] = f2bf(g);
            L.us[v] = f2bf(g - bf2f(H.us[v]));
        }
        *reinterpret_cast<uint4*>(mhi + (size_t)node * 128 + base) = H.v;
        *reinterpret_cast<uint4*>(mlo + (size_t)node * 128 + base) = L.v;
    } else {
        union { float f[4]; float4 v; } O;
#pragma unroll
        for (int v = 0; v < VPL; v++) O.f[v] = acc[v] * inv + bvec[base + v];
        *reinterpret_cast<float4*>(out + (size_t)node * D + base) = O.v;
    }
}

// ---------------- launch ------------------------------------------------------
extern "C" void kernel_launch(void* const* d_in, const int* in_sizes, int n_in,
                              void* d_out, int out_size, void* d_ws, size_t ws_size,
                              hipStream_t stream)
{
    const float* x     = (const float*)d_in[0];
    const float* W0    = (const float*)d_in[1];
    const float* b0    = (const float*)d_in[2];
    const float* Wq1   = (const float*)d_in[3];
    const float* bq1   = (const float*)d_in[4];
    const float* Wp1   = (const float*)d_in[5];
    const float* bp1   = (const float*)d_in[6];
    const float* a1    = (const float*)d_in[7];
    const float* bg2   = (const float*)d_in[8];
    const float* Wq2   = (const float*)d_in[9];
    const float* bq2   = (const float*)d_in[10];
    const float* Wp2   = (const float*)d_in[11];
    const float* bp2   = (const float*)d_in[12];
    const float* a2    = (const float*)d_in[13];
    const float* b_out = (const float*)d_in[14];
    const int*   src   = (const int*)d_in[15];
    const int*   dst   = (const int*)d_in[16];

    const int N = in_sizes[0] / 128;
    const int E = in_sizes[15];
    float* out = (float*)d_out;

    // workspace carve
    float* q_buf        = (float*)d_ws;                      // N*128 f32
    unsigned short* pb  = (unsigned short*)(q_buf + (size_t)N * 128);  // N*128 bf16
    unsigned short* Mhi = pb + (size_t)N * 128;
    unsigned short* Mlo = Mhi + (size_t)N * 128;
    unsigned short* P0  = Mlo + (size_t)N * 128;
    unsigned short* Pq1 = P0  + 128 * 128 * 2;
    unsigned short* Pp1 = Pq1 + 128 * 128 * 2;
    unsigned short* Pq2 = Pp1 + 128 * 128 * 2;
    unsigned short* Pp2 = Pq2 + 128 * 64 * 2;
    int* offs    = (int*)(Pp2 + 128 * 64 * 2);
    int* csr_src = offs + (N + 2);
    const int CB = (N + 15) / 16;          // coarse bins (<= 4096 for N<=65536)
    const int M  = CB * 64;
    int* gh    = csr_src + E;
    int* gscan = gh + M;
    int* bsum  = gscan + M;                // 1024 ints
    // pairs aliases q_buf (dead until gemm layer-1); int2-aligned (base of ws)
    int2* pairs = (int2*)q_buf;

    const int NB1 = (M + 255) / 256;       // <= 1024

    // 1) weight prepack
    pack_w<<<dim3(64, 5), 256, 0, stream>>>(W0, Wq1, Wp1, Wq2, Wp2,
                                            P0, Pq1, Pp1, Pq2, Pp2);
    // 2-7) CSR build (atomic-free two-level counting sort)
    hist_coarse<<<64, 256, 0, stream>>>(dst, gh, E, CB);
    scan1_kernel<<<NB1, 256, 0, stream>>>(gh, gscan, bsum, M);
    scan2_kernel<<<1, 1024, 0, stream>>>(bsum, NB1);
    scan3_kernel<<<NB1, 256, 0, stream>>>(gscan, bsum, M);
    scatter_coarse<<<64, 256, 0, stream>>>(src, dst, gscan, pairs, E, CB);
    finalize_kernel<<<(CB + 3) / 4, 256, 0, stream>>>(pairs, gscan, offs, csr_src, N, E, CB);

    const int GB64 = (N + 63) / 64;
    const int GGAT = (N + 15) / 16;

    // 8) layer 0: m1 = gelu(x@W0 + b0) -> Mhi/Mlo
    mfma_gemm<128, false, 0><<<GB64, 256, 0, stream>>>(
        x, nullptr, nullptr, P0, b0, nullptr, nullptr,
        nullptr, nullptr, Mhi, Mlo, N);
    // 9) layer 1 projections: q1 fp32 + p1 bf16 in ONE pass over A
    mfma_gemm<128, true, 1><<<GB64, 256, 0, stream>>>(
        nullptr, Mhi, Mlo, Pq1, bq1, Pp1, bp1,
        q_buf, pb, nullptr, nullptr, N);
    // 10) layer 1 GAT -> m2 = gelu(h1 + bg2) -> Mhi/Mlo
    gat_agg<128, 0><<<GGAT, 256, 0, stream>>>(
        q_buf, pb, a1, bg2, offs, csr_src,
        nullptr, Mhi, Mlo, N);
    // 11) layer 2 projections: q2 fp32 + p2 bf16 in ONE pass over A
    mfma_gemm<64, true, 1><<<GB64, 256, 0, stream>>>(
        nullptr, Mhi, Mlo, Pq2, bq2, Pp2, bp2,
        q_buf, pb, nullptr, nullptr, N);
    // 12) layer 2 GAT + b_out -> d_out
    gat_agg<64, 1><<<GGAT, 256, 0, stream>>>(
        q_buf, pb, a2, b_out, offs, csr_src,
        out, nullptr, nullptr, N);
}